// Round 1
// baseline (59001.996 us; speedup 1.0000x reference)
//
#include <hip/hip_runtime.h>
#include <cstdio>

#define B_ 32
#define I_ 12
#define V_ 128
#define H_ 32
#define T_ 100
#define NH_ 4096
#define G3_ 12288

// ---------------- support = adj / (rowsum + 1e-6) ----------------
__global__ __launch_bounds__(128) void support_k(const float* __restrict__ adj,
                                                 float* __restrict__ sup) {
  int w = blockIdx.x, v = threadIdx.x;
  float a = adj[w * V_ + v];
  float s = a;
#pragma unroll
  for (int off = 32; off; off >>= 1) s += __shfl_down(s, off);
  __shared__ float red[2];
  if ((v & 63) == 0) red[v >> 6] = s;
  __syncthreads();
  float tot = red[0] + red[1];
  sup[w * V_ + v] = a / (tot + 1e-6f);
}

// ---------------- S2T[u*V + w] = (support @ support)[w,u] ----------------
__global__ __launch_bounds__(128) void s2t_k(const float* __restrict__ sup,
                                             float* __restrict__ s2t) {
  __shared__ float row[V_];
  int w = blockIdx.x, u = threadIdx.x;
  row[u] = sup[w * V_ + u];
  __syncthreads();
  float s = 0.f;
#pragma unroll 4
  for (int v = 0; v < V_; ++v) s += row[v] * sup[v * V_ + u];
  s2t[u * V_ + w] = s;
}

// ---------------- conv + fused double graph-conv -> repr_all[(t*B+b), n] ----------------
__global__ __launch_bounds__(256) void conv_repr_k(const float* __restrict__ x,
                                                   const float* __restrict__ conv_w,
                                                   const float* __restrict__ conv_b,
                                                   const float* __restrict__ s2t,
                                                   float* __restrict__ repr_all) {
  int blk = blockIdx.x;
  int t = blk / B_, b = blk % B_;
  __shared__ float xs[I_][V_];
  __shared__ float xin[H_][V_];
  __shared__ float cw[H_ * I_];
  int tid = threadIdx.x;
  for (int e = tid; e < I_ * V_; e += 256) {
    int i = e >> 7, v = e & 127;
    xs[i][v] = x[(((size_t)b * I_ + i) * V_ + v) * T_ + t];
  }
  for (int e = tid; e < H_ * I_; e += 256) cw[e] = conv_w[e];
  __syncthreads();
  for (int e = tid; e < H_ * V_; e += 256) {
    int hh = e >> 7, v = e & 127;
    float s = conv_b[hh];
#pragma unroll
    for (int i = 0; i < I_; ++i) s += cw[hh * I_ + i] * xs[i][v];
    xin[hh][v] = s;
  }
  __syncthreads();
  // repr[n = h*V + w] = sum_u xin[h][u] * S2[w,u]  (S2 stored transposed)
  int w = tid & 127;
  int h0 = tid >> 7;  // 0..1, handles h = h0 + 2j
  float acc[16];
#pragma unroll
  for (int j = 0; j < 16; ++j) acc[j] = 0.f;
  for (int u = 0; u < V_; ++u) {
    float sv = s2t[u * V_ + w];
#pragma unroll
    for (int j = 0; j < 16; ++j) acc[j] += sv * xin[h0 + 2 * j][u];
  }
  size_t row = (size_t)(t * B_ + b) * NH_;
#pragma unroll
  for (int j = 0; j < 16; ++j) {
    int n = (h0 + 2 * j) * V_ + w;
    repr_all[row + n] = acc[j];
  }
}

// ---------------- fp32 GEMM: C[m,n] = sum_k A[m,k]*Bm[n,k] + bias[n] ----------------
#define BM 64
#define BN 64
#define BK 16
__global__ __launch_bounds__(256) void sgemm_nt(const float* __restrict__ A,
                                                const float* __restrict__ Bm,
                                                const float* __restrict__ bias,
                                                float* __restrict__ C,
                                                int M, int N, int K) {
  __shared__ float As[BK][BM + 1];
  __shared__ float Bs[BK][BN + 1];
  int bm = blockIdx.y * BM, bn = blockIdx.x * BN;
  int tid = threadIdx.x;
  int tn = (tid & 15) * 4;
  int tm = (tid >> 4) * 4;
  float acc[4][4] = {{0.f}};
  for (int k0 = 0; k0 < K; k0 += BK) {
    for (int e = tid; e < BM * BK; e += 256) {
      int m = e >> 4, k = e & 15;
      int gm = bm + m;
      As[k][m] = (gm < M) ? A[(size_t)gm * K + k0 + k] : 0.f;
    }
    for (int e = tid; e < BN * BK; e += 256) {
      int n = e >> 4, k = e & 15;
      Bs[k][n] = Bm[(size_t)(bn + n) * K + k0 + k];  // N always multiple of BN here
    }
    __syncthreads();
#pragma unroll
    for (int k = 0; k < BK; ++k) {
      float a[4], bv[4];
#pragma unroll
      for (int i = 0; i < 4; i++) a[i] = As[k][tm + i];
#pragma unroll
      for (int j = 0; j < 4; j++) bv[j] = Bs[k][tn + j];
#pragma unroll
      for (int i = 0; i < 4; i++)
#pragma unroll
        for (int j = 0; j < 4; j++) acc[i][j] += a[i] * bv[j];
    }
    __syncthreads();
  }
#pragma unroll
  for (int i = 0; i < 4; i++) {
    int gm = bm + tm + i;
    if (gm >= M) continue;
#pragma unroll
    for (int j = 0; j < 4; j++) {
      int gn = bn + tn + j;
      C[(size_t)gm * N + gn] = acc[i][j] + bias[gn];
    }
  }
}

// ---------------- GRU gate ----------------
__global__ __launch_bounds__(256) void gru_gate_k(const float* __restrict__ gx_all,
                                                  const float* __restrict__ gh,
                                                  float* __restrict__ h,
                                                  float* __restrict__ hs_all, int t) {
  int idx = blockIdx.x * 256 + threadIdx.x;  // < B_*NH_
  int b = idx >> 12, n = idx & (NH_ - 1);
  const float* gxr = gx_all + (size_t)(t * B_ + b) * G3_;
  const float* ghr = gh + (size_t)b * G3_;
  float xr = gxr[n], xz = gxr[NH_ + n], xn = gxr[2 * NH_ + n];
  float hr = ghr[n], hz = ghr[NH_ + n], hn = ghr[2 * NH_ + n];
  float hv = h[idx];
  float r = 1.f / (1.f + __expf(-(xr + hr)));
  float z = 1.f / (1.f + __expf(-(xz + hz)));
  float nn = tanhf(xn + r * hn);
  float hnew = (1.f - z) * nn + z * hv;
  h[idx] = hnew;
  hs_all[(size_t)(t * B_ + b) * NH_ + n] = hnew;
}

__global__ __launch_bounds__(256) void init_h_k(const float* __restrict__ h0,
                                                float* __restrict__ h) {
  int idx = blockIdx.x * 256 + threadIdx.x;
  h[idx] = h0[idx & (NH_ - 1)];
}

// ---------------- (t*B+b, n) -> (b, n, t) tile transpose ----------------
__global__ __launch_bounds__(256) void transpose_tn_k(const float* __restrict__ src,
                                                      float* __restrict__ dst) {
  __shared__ float tile[64][65];
  int n0 = blockIdx.x * 64, t0 = blockIdx.y * 64, b = blockIdx.z;
  int tid = threadIdx.x;
  for (int e = tid; e < 64 * 64; e += 256) {
    int n = e & 63, t = e >> 6;
    int gt = t0 + t;
    if (gt < T_) tile[t][n] = src[((size_t)gt * B_ + b) * NH_ + n0 + n];
  }
  __syncthreads();
  for (int e = tid; e < 64 * 64; e += 256) {
    int t = e & 63, n = e >> 6;
    int gt = t0 + t;
    if (gt < T_) dst[((size_t)b * NH_ + n0 + n) * T_ + gt] = tile[t][n];
  }
}

__global__ __launch_bounds__(256) void copy_k(const float* __restrict__ src,
                                              float* __restrict__ dst, int n) {
  int i = blockIdx.x * 256 + threadIdx.x;
  if (i < n) dst[i] = src[i];
}

// ---------------- classifier ----------------
__global__ __launch_bounds__(256) void cls1_k(const float* __restrict__ h,
                                              const float* __restrict__ w1,
                                              const float* __restrict__ b1,
                                              float* __restrict__ tmp) {
  int gtid = blockIdx.x * 256 + threadIdx.x;
  int wid = gtid >> 6, lane = gtid & 63;
  if (wid >= B_ * 300) return;
  int b = wid / 300, j = wid % 300;
  const float* hr = h + (size_t)b * NH_;
  const float* wr = w1 + (size_t)j * NH_;
  float s = 0.f;
  for (int k = lane; k < NH_; k += 64) s += hr[k] * wr[k];
#pragma unroll
  for (int off = 32; off; off >>= 1) s += __shfl_down(s, off);
  if (lane == 0) { s += b1[j]; tmp[b * 300 + j] = fmaxf(s, 0.f); }
}

__global__ __launch_bounds__(64) void cls2_k(const float* __restrict__ tmp,
                                             const float* __restrict__ w2,
                                             const float* __restrict__ b2,
                                             float* __restrict__ out) {
  int idx = threadIdx.x;
  if (idx < B_ * 2) {
    int b = idx >> 1, c = idx & 1;
    float s = b2[c];
    for (int j = 0; j < 300; ++j) s += tmp[b * 300 + j] * w2[c * 300 + j];
    out[idx] = s;
  }
}

extern "C" void kernel_launch(void* const* d_in, const int* in_sizes, int n_in,
                              void* d_out, int out_size, void* d_ws, size_t ws_size,
                              hipStream_t stream) {
  const float* x      = (const float*)d_in[0];
  const float* adj    = (const float*)d_in[1];
  // d_in[2] = mask (unused by reference)
  const float* h0     = (const float*)d_in[3];
  const float* conv_w = (const float*)d_in[4];
  const float* conv_b = (const float*)d_in[5];
  const float* w_ih   = (const float*)d_in[6];
  const float* w_hh   = (const float*)d_in[7];
  const float* b_ih   = (const float*)d_in[8];
  const float* b_hh   = (const float*)d_in[9];
  const float* cls_w1 = (const float*)d_in[10];
  const float* cls_b1 = (const float*)d_in[11];
  const float* cls_w2 = (const float*)d_in[12];
  const float* cls_b2 = (const float*)d_in[13];
  float* out = (float*)d_out;

  float* ws = (float*)d_ws;
  size_t off = 0;
  float* sup      = ws + off; off += (size_t)V_ * V_;
  float* s2t      = ws + off; off += (size_t)V_ * V_;
  float* repr_all = ws + off; off += (size_t)T_ * B_ * NH_;   // 52.4 MB
  float* hs_all   = ws + off; off += (size_t)T_ * B_ * NH_;   // 52.4 MB
  float* gx_all   = ws + off; off += (size_t)T_ * B_ * G3_;   // 157.3 MB
  float* h        = ws + off; off += (size_t)B_ * NH_;
  float* gh       = ws + off; off += (size_t)B_ * G3_;
  float* ctmp     = ws + off; off += (size_t)B_ * 300;
  size_t need = off * sizeof(float);
  if (ws_size < need) {
    // Canary: a failure with absmax == 0.4257 (all-zero output) means ws too small.
    fprintf(stderr, "athena-hip: ws_size=%zu < need=%zu - output left zero\n",
            ws_size, need);
    return;
  }

  support_k<<<V_, V_, 0, stream>>>(adj, sup);
  s2t_k<<<V_, V_, 0, stream>>>(sup, s2t);
  conv_repr_k<<<T_ * B_, 256, 0, stream>>>(x, conv_w, conv_b, s2t, repr_all);
  // Big batched input GEMM: gx for ALL timesteps at once (repr doesn't depend on h)
  sgemm_nt<<<dim3(G3_ / BN, (T_ * B_ + BM - 1) / BM), 256, 0, stream>>>(
      repr_all, w_ih, b_ih, gx_all, T_ * B_, G3_, NH_);
  init_h_k<<<(B_ * NH_) / 256, 256, 0, stream>>>(h0, h);
  for (int t = 0; t < T_; ++t) {
    sgemm_nt<<<dim3(G3_ / BN, 1), 256, 0, stream>>>(h, w_hh, b_hh, gh, B_, G3_, NH_);
    gru_gate_k<<<(B_ * NH_) / 256, 256, 0, stream>>>(gx_all, gh, h, hs_all, t);
  }
  transpose_tn_k<<<dim3(NH_ / 64, (T_ + 63) / 64, B_), 256, 0, stream>>>(repr_all, out);
  transpose_tn_k<<<dim3(NH_ / 64, (T_ + 63) / 64, B_), 256, 0, stream>>>(
      hs_all, out + (size_t)B_ * NH_ * T_);
  copy_k<<<(B_ * NH_) / 256, 256, 0, stream>>>(h, out + (size_t)2 * B_ * NH_ * T_, B_ * NH_);
  cls1_k<<<(B_ * 300 * 64 + 255) / 256, 256, 0, stream>>>(h, cls_w1, cls_b1, ctmp);
  cls2_k<<<1, 64, 0, stream>>>(ctmp, cls_w2, cls_b2,
                               out + (size_t)2 * B_ * NH_ * T_ + B_ * NH_);
}

// Round 2
// 7532.829 us; speedup vs baseline: 7.8326x; 7.8326x over previous
//
#include <hip/hip_runtime.h>
#include <cstdio>

#define B_ 32
#define I_ 12
#define V_ 128
#define H_ 32
#define T_ 100
#define NH_ 4096
#define G3_ 12288

typedef __attribute__((ext_vector_type(8))) short short8;
typedef __attribute__((ext_vector_type(4))) float floatx4;

__device__ __forceinline__ unsigned short f2bf(float f) {
  unsigned int u = __float_as_uint(f);
  unsigned int r = (u + 0x7FFFu + ((u >> 16) & 1u)) >> 16;  // RNE
  return (unsigned short)r;
}
__device__ __forceinline__ float bf2f(unsigned short h) {
  return __uint_as_float(((unsigned int)h) << 16);
}

// ---------------- support = adj / (rowsum + 1e-6) ----------------
__global__ __launch_bounds__(128) void support_k(const float* __restrict__ adj,
                                                 float* __restrict__ sup) {
  int w = blockIdx.x, v = threadIdx.x;
  float a = adj[w * V_ + v];
  float s = a;
#pragma unroll
  for (int off = 32; off; off >>= 1) s += __shfl_down(s, off);
  __shared__ float red[2];
  if ((v & 63) == 0) red[v >> 6] = s;
  __syncthreads();
  float tot = red[0] + red[1];
  sup[w * V_ + v] = a / (tot + 1e-6f);
}

// ---------------- S2T[u*V + w] = (support @ support)[w,u] ----------------
__global__ __launch_bounds__(128) void s2t_k(const float* __restrict__ sup,
                                             float* __restrict__ s2t) {
  __shared__ float row[V_];
  int w = blockIdx.x, u = threadIdx.x;
  row[u] = sup[w * V_ + u];
  __syncthreads();
  float s = 0.f;
#pragma unroll 4
  for (int v = 0; v < V_; ++v) s += row[v] * sup[v * V_ + u];
  s2t[u * V_ + w] = s;
}

// ------- conv + double graph-conv -> repr hi/lo bf16, row (t*B+b), col n -------
__global__ __launch_bounds__(256) void conv_repr_k(const float* __restrict__ x,
                                                   const float* __restrict__ conv_w,
                                                   const float* __restrict__ conv_b,
                                                   const float* __restrict__ s2t,
                                                   unsigned short* __restrict__ rhi,
                                                   unsigned short* __restrict__ rlo) {
  int blk = blockIdx.x;
  int t = blk / B_, b = blk % B_;
  __shared__ float xs[I_][V_];
  __shared__ float xin[H_][V_];
  __shared__ float cw[H_ * I_];
  int tid = threadIdx.x;
  for (int e = tid; e < I_ * V_; e += 256) {
    int i = e >> 7, v = e & 127;
    xs[i][v] = x[(((size_t)b * I_ + i) * V_ + v) * T_ + t];
  }
  for (int e = tid; e < H_ * I_; e += 256) cw[e] = conv_w[e];
  __syncthreads();
  for (int e = tid; e < H_ * V_; e += 256) {
    int hh = e >> 7, v = e & 127;
    float s = conv_b[hh];
#pragma unroll
    for (int i = 0; i < I_; ++i) s += cw[hh * I_ + i] * xs[i][v];
    xin[hh][v] = s;
  }
  __syncthreads();
  int w = tid & 127;
  int h0 = tid >> 7;
  float acc[16];
#pragma unroll
  for (int j = 0; j < 16; ++j) acc[j] = 0.f;
  for (int u = 0; u < V_; ++u) {
    float sv = s2t[u * V_ + w];
#pragma unroll
    for (int j = 0; j < 16; ++j) acc[j] += sv * xin[h0 + 2 * j][u];
  }
  size_t row = (size_t)(t * B_ + b) * NH_;
#pragma unroll
  for (int j = 0; j < 16; ++j) {
    int n = (h0 + 2 * j) * V_ + w;
    float v = acc[j];
    unsigned short hi = f2bf(v);
    unsigned short lo = f2bf(v - bf2f(hi));
    rhi[row + n] = hi;
    rlo[row + n] = lo;
  }
}

// ---------------- fp32 -> bf16(hi) bulk convert (w_hh) ----------------
__global__ __launch_bounds__(256) void cvt_bf16_k(const float* __restrict__ src,
                                                  unsigned short* __restrict__ dst,
                                                  int n4) {
  int i = blockIdx.x * 256 + threadIdx.x;
  if (i >= n4) return;
  float4 v = *(const float4*)&src[(size_t)i * 4];
  ushort4 o;
  o.x = f2bf(v.x); o.y = f2bf(v.y); o.z = f2bf(v.z); o.w = f2bf(v.w);
  *(ushort4*)&dst[(size_t)i * 4] = o;
}

// ------- big GEMM: gx[m,n] = sum_k repr[m,k] * w_ih[n,k]  (bf16 MFMA, A hi+lo) -------
__global__ __launch_bounds__(256) void gemm_big(const unsigned short* __restrict__ Ahi,
                                                const unsigned short* __restrict__ Alo,
                                                const float* __restrict__ Wih,
                                                unsigned short* __restrict__ gx) {
  __shared__ __align__(16) unsigned short As_hi[128][40];
  __shared__ __align__(16) unsigned short As_lo[128][40];
  __shared__ __align__(16) unsigned short Bs[128][40];
  int bm = blockIdx.y * 128, bn = blockIdx.x * 128;
  int tid = threadIdx.x;
  int wv = tid >> 6, lane = tid & 63, quad = lane >> 4, l15 = lane & 15;
  int m0w = (wv >> 1) * 64, n0w = (wv & 1) * 64;
  floatx4 acc[4][4];
#pragma unroll
  for (int i = 0; i < 4; ++i)
#pragma unroll
    for (int j = 0; j < 4; ++j) acc[i][j] = (floatx4){0.f, 0.f, 0.f, 0.f};

  for (int k0 = 0; k0 < NH_; k0 += 32) {
#pragma unroll
    for (int r = 0; r < 2; ++r) {
      int c = tid + 256 * r;             // 512 chunks of 8 bf16
      int row = c >> 2, kc = (c & 3) * 8;
      *(uint4*)&As_hi[row][kc] = *(const uint4*)&Ahi[(size_t)(bm + row) * NH_ + k0 + kc];
      *(uint4*)&As_lo[row][kc] = *(const uint4*)&Alo[(size_t)(bm + row) * NH_ + k0 + kc];
    }
#pragma unroll
    for (int r = 0; r < 4; ++r) {
      int c = tid + 256 * r;             // 1024 chunks of 4 floats
      int row = c >> 3, kc = (c & 7) * 4;
      float4 w4 = *(const float4*)&Wih[(size_t)(bn + row) * NH_ + k0 + kc];
      ushort4 h4;
      h4.x = f2bf(w4.x); h4.y = f2bf(w4.y); h4.z = f2bf(w4.z); h4.w = f2bf(w4.w);
      *(ushort4*)&Bs[row][kc] = h4;
    }
    __syncthreads();
    short8 a_hi[4], a_lo[4], bfr[4];
#pragma unroll
    for (int i = 0; i < 4; ++i) {
      a_hi[i] = *(const short8*)&As_hi[m0w + i * 16 + l15][quad * 8];
      a_lo[i] = *(const short8*)&As_lo[m0w + i * 16 + l15][quad * 8];
      bfr[i]  = *(const short8*)&Bs[n0w + i * 16 + l15][quad * 8];
    }
#pragma unroll
    for (int i = 0; i < 4; ++i)
#pragma unroll
      for (int j = 0; j < 4; ++j) {
        acc[i][j] = __builtin_amdgcn_mfma_f32_16x16x32_bf16(a_hi[i], bfr[j], acc[i][j], 0, 0, 0);
        acc[i][j] = __builtin_amdgcn_mfma_f32_16x16x32_bf16(a_lo[i], bfr[j], acc[i][j], 0, 0, 0);
      }
    __syncthreads();
  }
#pragma unroll
  for (int i = 0; i < 4; ++i)
#pragma unroll
    for (int j = 0; j < 4; ++j)
#pragma unroll
      for (int r = 0; r < 4; ++r) {
        int row = bm + m0w + i * 16 + quad * 4 + r;
        int col = bn + n0w + j * 16 + l15;
        gx[(size_t)row * G3_ + col] = f2bf(acc[i][j][r]);
      }
}

// ------- recurrent GEMM: gh_part[kh][b][n] = sum_{k in kh} h[b,k]*w_hh[n,k] -------
__global__ __launch_bounds__(256) void gru_gemm(const unsigned short* __restrict__ hhi,
                                                const unsigned short* __restrict__ hlo,
                                                const unsigned short* __restrict__ Whh,
                                                float* __restrict__ ghp) {
  int bx = blockIdx.x;   // 192 n-tiles of 64
  int kh = blockIdx.y;   // 4 K-splits of 1024
  int tid = threadIdx.x;
  int wv = tid >> 6, lane = tid & 63, quad = lane >> 4, l15 = lane & 15;
  int n0 = bx * 64 + wv * 16;
  floatx4 acc[2];
  acc[0] = (floatx4){0.f, 0.f, 0.f, 0.f};
  acc[1] = (floatx4){0.f, 0.f, 0.f, 0.f};
  int kbase = kh * 1024;
#pragma unroll 4
  for (int it = 0; it < 32; ++it) {
    int k = kbase + it * 32 + quad * 8;
    short8 bfr = *(const short8*)&Whh[(size_t)(n0 + l15) * NH_ + k];
#pragma unroll
    for (int mi = 0; mi < 2; ++mi) {
      short8 ah = *(const short8*)&hhi[(size_t)(mi * 16 + l15) * NH_ + k];
      short8 al = *(const short8*)&hlo[(size_t)(mi * 16 + l15) * NH_ + k];
      acc[mi] = __builtin_amdgcn_mfma_f32_16x16x32_bf16(ah, bfr, acc[mi], 0, 0, 0);
      acc[mi] = __builtin_amdgcn_mfma_f32_16x16x32_bf16(al, bfr, acc[mi], 0, 0, 0);
    }
  }
#pragma unroll
  for (int mi = 0; mi < 2; ++mi)
#pragma unroll
    for (int r = 0; r < 4; ++r) {
      int m = mi * 16 + quad * 4 + r;
      ghp[((size_t)kh * B_ + m) * G3_ + n0 + l15] = acc[mi][r];
    }
}

// ---------------- GRU gate (reduces K-split partials, adds biases) ----------------
__global__ __launch_bounds__(256) void gru_gate(const unsigned short* __restrict__ gx,
                                                const float* __restrict__ ghp,
                                                const float* __restrict__ b_ih,
                                                const float* __restrict__ b_hh,
                                                float* __restrict__ h,
                                                unsigned short* __restrict__ hhi,
                                                unsigned short* __restrict__ hlo,
                                                float* __restrict__ hs_all, int t) {
  int idx = blockIdx.x * 256 + threadIdx.x;  // B_*NH_
  int b = idx >> 12, n = idx & (NH_ - 1);
  size_t g0 = (size_t)(t * B_ + b) * G3_;
  float xr = bf2f(gx[g0 + n]) + b_ih[n];
  float xz = bf2f(gx[g0 + NH_ + n]) + b_ih[NH_ + n];
  float xn = bf2f(gx[g0 + 2 * NH_ + n]) + b_ih[2 * NH_ + n];
  float hr = 0.f, hz = 0.f, hn = 0.f;
#pragma unroll
  for (int kh = 0; kh < 4; ++kh) {
    size_t base = ((size_t)kh * B_ + b) * G3_;
    hr += ghp[base + n];
    hz += ghp[base + NH_ + n];
    hn += ghp[base + 2 * NH_ + n];
  }
  hr += b_hh[n]; hz += b_hh[NH_ + n]; hn += b_hh[2 * NH_ + n];
  float r = 1.f / (1.f + __expf(-(xr + hr)));
  float z = 1.f / (1.f + __expf(-(xz + hz)));
  float nn = tanhf(xn + r * hn);
  float hv = h[idx];
  float hnew = (1.f - z) * nn + z * hv;
  h[idx] = hnew;
  unsigned short hi = f2bf(hnew);
  hhi[idx] = hi;
  hlo[idx] = f2bf(hnew - bf2f(hi));
  hs_all[(size_t)(t * B_ + b) * NH_ + n] = hnew;
}

__global__ __launch_bounds__(256) void init_h_k(const float* __restrict__ h0,
                                                float* __restrict__ h,
                                                unsigned short* __restrict__ hhi,
                                                unsigned short* __restrict__ hlo) {
  int idx = blockIdx.x * 256 + threadIdx.x;
  float v = h0[idx & (NH_ - 1)];
  h[idx] = v;
  unsigned short hi = f2bf(v);
  hhi[idx] = hi;
  hlo[idx] = f2bf(v - bf2f(hi));
}

// ---------------- (t*B+b, n) fp32 -> (b, n, t) ----------------
__global__ __launch_bounds__(256) void transpose_f32_k(const float* __restrict__ src,
                                                       float* __restrict__ dst) {
  __shared__ float tile[64][65];
  int n0 = blockIdx.x * 64, t0 = blockIdx.y * 64, b = blockIdx.z;
  int tid = threadIdx.x;
  for (int e = tid; e < 64 * 64; e += 256) {
    int n = e & 63, t = e >> 6;
    int gt = t0 + t;
    if (gt < T_) tile[t][n] = src[((size_t)gt * B_ + b) * NH_ + n0 + n];
  }
  __syncthreads();
  for (int e = tid; e < 64 * 64; e += 256) {
    int t = e & 63, n = e >> 6;
    int gt = t0 + t;
    if (gt < T_) dst[((size_t)b * NH_ + n0 + n) * T_ + gt] = tile[t][n];
  }
}

// ---------------- (t*B+b, n) bf16 hi/lo -> (b, n, t) fp32 ----------------
__global__ __launch_bounds__(256) void transpose_bf_k(const unsigned short* __restrict__ hi,
                                                      const unsigned short* __restrict__ lo,
                                                      float* __restrict__ dst) {
  __shared__ float tile[64][65];
  int n0 = blockIdx.x * 64, t0 = blockIdx.y * 64, b = blockIdx.z;
  int tid = threadIdx.x;
  for (int e = tid; e < 64 * 64; e += 256) {
    int n = e & 63, t = e >> 6;
    int gt = t0 + t;
    if (gt < T_) {
      size_t src = ((size_t)gt * B_ + b) * NH_ + n0 + n;
      tile[t][n] = bf2f(hi[src]) + bf2f(lo[src]);
    }
  }
  __syncthreads();
  for (int e = tid; e < 64 * 64; e += 256) {
    int t = e & 63, n = e >> 6;
    int gt = t0 + t;
    if (gt < T_) dst[((size_t)b * NH_ + n0 + n) * T_ + gt] = tile[t][n];
  }
}

__global__ __launch_bounds__(256) void copy_k(const float* __restrict__ src,
                                              float* __restrict__ dst, int n) {
  int i = blockIdx.x * 256 + threadIdx.x;
  if (i < n) dst[i] = src[i];
}

// ---------------- classifier ----------------
__global__ __launch_bounds__(256) void cls1_k(const float* __restrict__ h,
                                              const float* __restrict__ w1,
                                              const float* __restrict__ b1,
                                              float* __restrict__ tmp) {
  int gtid = blockIdx.x * 256 + threadIdx.x;
  int wid = gtid >> 6, lane = gtid & 63;
  if (wid >= B_ * 300) return;
  int b = wid / 300, j = wid % 300;
  const float* hr = h + (size_t)b * NH_;
  const float* wr = w1 + (size_t)j * NH_;
  float s = 0.f;
  for (int k = lane; k < NH_; k += 64) s += hr[k] * wr[k];
#pragma unroll
  for (int off = 32; off; off >>= 1) s += __shfl_down(s, off);
  if (lane == 0) { s += b1[j]; tmp[b * 300 + j] = fmaxf(s, 0.f); }
}

__global__ __launch_bounds__(64) void cls2_k(const float* __restrict__ tmp,
                                             const float* __restrict__ w2,
                                             const float* __restrict__ b2,
                                             float* __restrict__ out) {
  int idx = threadIdx.x;
  if (idx < B_ * 2) {
    int b = idx >> 1, c = idx & 1;
    float s = b2[c];
    for (int j = 0; j < 300; ++j) s += tmp[b * 300 + j] * w2[c * 300 + j];
    out[idx] = s;
  }
}

extern "C" void kernel_launch(void* const* d_in, const int* in_sizes, int n_in,
                              void* d_out, int out_size, void* d_ws, size_t ws_size,
                              hipStream_t stream) {
  const float* x      = (const float*)d_in[0];
  const float* adj    = (const float*)d_in[1];
  const float* h0     = (const float*)d_in[3];
  const float* conv_w = (const float*)d_in[4];
  const float* conv_b = (const float*)d_in[5];
  const float* w_ih   = (const float*)d_in[6];
  const float* w_hh   = (const float*)d_in[7];
  const float* b_ih   = (const float*)d_in[8];
  const float* b_hh   = (const float*)d_in[9];
  const float* cls_w1 = (const float*)d_in[10];
  const float* cls_b1 = (const float*)d_in[11];
  const float* cls_w2 = (const float*)d_in[12];
  const float* cls_b2 = (const float*)d_in[13];
  float* out = (float*)d_out;

  char* ws = (char*)d_ws;
  size_t off = 0;
  auto alloc = [&](size_t bytes) { char* p = ws + off; off += (bytes + 255) & ~(size_t)255; return p; };
  float* sup            = (float*)alloc((size_t)V_ * V_ * 4);
  float* s2t            = (float*)alloc((size_t)V_ * V_ * 4);
  unsigned short* rhi   = (unsigned short*)alloc((size_t)T_ * B_ * NH_ * 2);   // 26.2 MB
  unsigned short* rlo   = (unsigned short*)alloc((size_t)T_ * B_ * NH_ * 2);   // 26.2 MB
  unsigned short* whh_h = (unsigned short*)alloc((size_t)G3_ * NH_ * 2);       // 100.7 MB
  unsigned short* gx    = (unsigned short*)alloc((size_t)T_ * B_ * G3_ * 2);   // 78.6 MB
  float* hs_all         = (float*)alloc((size_t)T_ * B_ * NH_ * 4);            // 52.4 MB
  float* h              = (float*)alloc((size_t)B_ * NH_ * 4);
  unsigned short* hhi   = (unsigned short*)alloc((size_t)B_ * NH_ * 2);
  unsigned short* hlo   = (unsigned short*)alloc((size_t)B_ * NH_ * 2);
  float* ghp            = (float*)alloc((size_t)4 * B_ * G3_ * 4);             // 6.3 MB
  float* ctmp           = (float*)alloc((size_t)B_ * 300 * 4);
  if (ws_size < off) {
    fprintf(stderr, "athena-hip: ws_size=%zu < need=%zu - output left zero\n", ws_size, off);
    return;
  }

  support_k<<<V_, V_, 0, stream>>>(adj, sup);
  s2t_k<<<V_, V_, 0, stream>>>(sup, s2t);
  conv_repr_k<<<T_ * B_, 256, 0, stream>>>(x, conv_w, conv_b, s2t, rhi, rlo);
  cvt_bf16_k<<<(G3_ * NH_ / 4 + 255) / 256, 256, 0, stream>>>(w_hh, whh_h, G3_ * NH_ / 4);
  gemm_big<<<dim3(G3_ / 128, (T_ * B_) / 128), 256, 0, stream>>>(rhi, rlo, w_ih, gx);
  init_h_k<<<(B_ * NH_) / 256, 256, 0, stream>>>(h0, h, hhi, hlo);
  for (int t = 0; t < T_; ++t) {
    gru_gemm<<<dim3(G3_ / 64, 4), 256, 0, stream>>>(hhi, hlo, whh_h, ghp);
    gru_gate<<<(B_ * NH_) / 256, 256, 0, stream>>>(gx, ghp, b_ih, b_hh, h, hhi, hlo, hs_all, t);
  }
  transpose_bf_k<<<dim3(NH_ / 64, (T_ + 63) / 64, B_), 256, 0, stream>>>(rhi, rlo, out);
  transpose_f32_k<<<dim3(NH_ / 64, (T_ + 63) / 64, B_), 256, 0, stream>>>(
      hs_all, out + (size_t)B_ * NH_ * T_);
  copy_k<<<(B_ * NH_) / 256, 256, 0, stream>>>(h, out + (size_t)2 * B_ * NH_ * T_, B_ * NH_);
  cls1_k<<<(B_ * 300 * 64 + 255) / 256, 256, 0, stream>>>(h, cls_w1, cls_b1, ctmp);
  cls2_k<<<1, 64, 0, stream>>>(ctmp, cls_w2, cls_b2,
                               out + (size_t)2 * B_ * NH_ * T_ + B_ * NH_);
}